// Round 6
// baseline (1411.972 us; speedup 1.0000x reference)
//
#include <hip/hip_runtime.h>
#include <hip/hip_bf16.h>

typedef __hip_bfloat16 bf16;
typedef __attribute__((ext_vector_type(4))) float f32x4;
typedef __attribute__((ext_vector_type(8))) short short8;
typedef __attribute__((ext_vector_type(4))) short short4v;

#define NEGBIG (-3.0e38f)

__device__ __forceinline__ unsigned short f2b(float x) {
  union { float f; unsigned int u; } v; v.f = x;
  unsigned int r = v.u + 0x7fffu + ((v.u >> 16) & 1u);
  return (unsigned short)(r >> 16);
}

__device__ __forceinline__ void gl16(const void* g, void* l) {
  __builtin_amdgcn_global_load_lds(
      (const __attribute__((address_space(1))) unsigned int*)g,
      (__attribute__((address_space(3))) unsigned int*)l, 16, 0, 0);
}

// bijective XCD-grouping swizzle (m204): contiguous tile range per XCD
__device__ __forceinline__ int xcd_swz(int orig, int nwg) {
  const int q = nwg >> 3, r = nwg & 7;
  const int xcd = orig & 7;
  const int base = (xcd < r) ? xcd * (q + 1) : r * (q + 1) + (xcd - r) * q;
  return base + (orig >> 3);
}

// stage one 256x32-bf16 K-tile pair (A 16KB @buf, B 16KB @buf+16384).
// LDS dest linear (gl16 requirement); global source 16B-slot XOR-permuted by
// (row>>1)&3 so the swizzled ds_read below is conflict-free (rule #21).
// 4 gl16 per thread (512 threads).
__device__ __forceinline__ void stage256(const char* Ab, const char* Bb,
                                         char* buf, int arow0, int brow0,
                                         int k0) {
  const int tid = threadIdx.x;
#pragma unroll
  for (int i = 0; i < 2; ++i) {
    const int g = tid + 512 * i;  // 0..1023 slots of 16B
    const int row = g >> 2;       // 0..255
    const int scol = ((g & 3) ^ ((row >> 1) & 3)) << 4;
    gl16(Ab + (size_t)(arow0 + row) * 1024 + k0 * 2 + scol, buf + g * 16);
    gl16(Bb + (size_t)(brow0 + row) * 1024 + k0 * 2 + scol,
         buf + 16384 + g * 16);
  }
}

// ---------------- weight f32 -> bf16 (row-major) ----------------
__global__ __launch_bounds__(256) void cvt_w_kernel(
    const float* __restrict__ a, const float* __restrict__ b,
    const float* __restrict__ c, const float* __restrict__ d,
    bf16* __restrict__ dst) {
  const int t = blockIdx.x * 256 + threadIdx.x;
  const float* srcs[4] = {a, b, c, d};
#pragma unroll
  for (int w = 0; w < 4; ++w) {
    const f32x4 v = *(const f32x4*)(srcs[w] + (size_t)t * 4);
    short4v o;
    o[0] = (short)f2b(v[0]); o[1] = (short)f2b(v[1]);
    o[2] = (short)f2b(v[2]); o[3] = (short)f2b(v[3]);
    *(short4v*)((short*)dst + (size_t)w * 262144 + (size_t)t * 4) = o;
  }
}

// ---------------- activation f32 -> bf16 (row-major [M][512]) -------------
__global__ __launch_bounds__(256) void cvt_a(const float* __restrict__ src,
                                             short* __restrict__ dst, int M) {
  const int g = blockIdx.x * 256 + threadIdx.x;
  const int row = g >> 6, k8 = g & 63;
  if (row >= M) return;
  const float* sp = src + (size_t)row * 512 + k8 * 8;
  const f32x4 lo = *(const f32x4*)sp;
  const f32x4 hi = *(const f32x4*)(sp + 4);
  short8 u;
  u[0] = (short)f2b(lo[0]); u[1] = (short)f2b(lo[1]);
  u[2] = (short)f2b(lo[2]); u[3] = (short)f2b(lo[3]);
  u[4] = (short)f2b(hi[0]); u[5] = (short)f2b(hi[1]);
  u[6] = (short)f2b(hi[2]); u[7] = (short)f2b(hi[3]);
  *(short8*)(dst + (size_t)row * 512 + k8 * 8) = u;
}

// ---- bias table -> per-(head, frag-element) layout, pads = NEGBIG ----
__global__ __launch_bounds__(256) void prep_rpbL(const float* __restrict__ btab,
                                                 float* __restrict__ rpbL) {
  const int g = blockIdx.x * 256 + threadIdx.x;
  const int lane = g & 63, mn = (g >> 6) & 15, h = g >> 10;
  const int m = mn >> 2, n = mn & 3, l15 = lane & 15, lg = lane >> 4;
  const int cc = n * 16 + l15;
  const int aj = cc / 7, bj = cc % 7;
  f32x4 o;
#pragma unroll
  for (int reg = 0; reg < 4; ++reg) {
    const int i = m * 16 + lg * 4 + reg;
    if (i < 49 && cc < 49) {
      const int t = (i / 7 - aj + 6) * 13 + (i % 7 - bj + 6);
      o[reg] = btab[t * 16 + h];
    } else {
      o[reg] = NEGBIG;
    }
  }
  ((f32x4*)rpbL)[g] = o;
}

// ---- mask -> per-(window, frag-element) layout, pads = 0 ----
__global__ __launch_bounds__(256) void prep_maskL(const float* __restrict__ mask,
                                                  float* __restrict__ maskL) {
  const int g = blockIdx.x * 256 + threadIdx.x;
  const int lane = g & 63, mn = (g >> 6) & 15, wm = g >> 10;
  const int m = mn >> 2, n = mn & 3, l15 = lane & 15, lg = lane >> 4;
  const int cc = n * 16 + l15;
  f32x4 o;
#pragma unroll
  for (int reg = 0; reg < 4; ++reg) {
    const int i = m * 16 + lg * 4 + reg;
    o[reg] = (i < 49 && cc < 49) ? mask[(size_t)wm * 2401 + i * 49 + cc] : 0.f;
  }
  ((f32x4*)maskL)[g] = o;
}

// ---------------- 256x256 ring-buffer GEMM, counted vmcnt -------------------
// MODE 0 (KQV): grid 6*gy, bn%6: cls = bn>>1 (0=K,1=Q,2=V^T), bnl = bn&1.
// MODE 1 (proj): grid 2*gy, bnl = bn&1, f32 output [r][512].
// 8 waves (2Mx4N), per-wave 128x64. LDS: 4-deep ring of 32KB K-tiles (128KB).
// Compute tile t from buf[t&3], stage tile t+2 into buf[(t+2)&3];
// end-of-iter wait = s_waitcnt vmcnt(4) (tile t+1 resident, t+2 in flight).
template <int MODE>
__global__ __launch_bounds__(512, 2) void gemm256(
    const short* __restrict__ Al, const short* __restrict__ Ag,
    const short* __restrict__ wbf, const float* __restrict__ bk,
    const float* __restrict__ bq, const float* __restrict__ bv, float qscale,
    bf16* __restrict__ k_ws, bf16* __restrict__ q_ws, bf16* __restrict__ vT_ws,
    float* __restrict__ fout, int M) {
  __shared__ char lds[131072];
  const int nwg = gridDim.x;
  const int t0 = xcd_swz(blockIdx.x, nwg);
  const int NB = (MODE == 0) ? 6 : 2;
  const int bn = t0 % NB, bm = t0 / NB;
  const int cls = (MODE == 0) ? (bn >> 1) : 3;
  const int bnl = bn & 1;
  const int tid = threadIdx.x, lane = tid & 63, wid = tid >> 6;
  const int wr = wid >> 2, wc = wid & 3, l15 = lane & 15, lg = lane >> 4;

  const char* Ab = (const char*)((MODE == 1) ? Al : ((cls == 1) ? Ag : Al));
  const char* Bb = (const char*)(wbf + (size_t)((MODE == 1) ? 3 : cls) * 262144);
  const int am0 = bm * 256, bn0 = bnl * 256;
  const bool swap = (MODE == 0) && (cls == 2);

  f32x4 acc[8][4];
#pragma unroll
  for (int m = 0; m < 8; ++m)
#pragma unroll
    for (int n = 0; n < 4; ++n) acc[m][n] = (f32x4){0.f, 0.f, 0.f, 0.f};

  // prologue: tiles 0,1
  stage256(Ab, Bb, lds, am0, bn0, 0);
  stage256(Ab, Bb, lds + 32768, am0, bn0, 32);
  asm volatile("s_waitcnt vmcnt(4)" ::: "memory");
  __builtin_amdgcn_s_barrier();
  __builtin_amdgcn_sched_barrier(0);

#pragma unroll 1
  for (int t = 0; t < 16; ++t) {
    if (t + 2 < 16)
      stage256(Ab, Bb, lds + ((t + 2) & 3) * 32768, am0, bn0, (t + 2) * 32);
    const char* base = lds + (t & 3) * 32768;
    const char* fa = swap ? base + 16384 : base;
    const char* fb = swap ? base : base + 16384;
    short8 af[8], bfr[4];
#pragma unroll
    for (int m = 0; m < 8; ++m) {
      const int r = wr * 128 + m * 16 + l15;
      af[m] = *(const short8*)(fa + r * 64 + ((lg ^ ((r >> 1) & 3)) << 4));
    }
#pragma unroll
    for (int n = 0; n < 4; ++n) {
      const int r = wc * 64 + n * 16 + l15;
      bfr[n] = *(const short8*)(fb + r * 64 + ((lg ^ ((r >> 1) & 3)) << 4));
    }
    __builtin_amdgcn_s_setprio(1);
#pragma unroll
    for (int m = 0; m < 8; ++m)
#pragma unroll
      for (int n = 0; n < 4; ++n)
        acc[m][n] = __builtin_amdgcn_mfma_f32_16x16x32_bf16(
            af[m], bfr[n], acc[m][n], 0, 0, 0);
    __builtin_amdgcn_s_setprio(0);
    if (t < 14) {
      asm volatile("s_waitcnt vmcnt(4)" ::: "memory");
    } else if (t == 14) {
      asm volatile("s_waitcnt vmcnt(0)" ::: "memory");
    }
    if (t < 15) {
      __builtin_amdgcn_s_barrier();
      __builtin_amdgcn_sched_barrier(0);
    }
  }

  // ---- epilogues ----
  if (MODE == 1) {
#pragma unroll
    for (int m = 0; m < 8; ++m) {
#pragma unroll
      for (int n = 0; n < 4; ++n) {
        const int c = bn0 + wc * 64 + n * 16 + l15;
        const float bvv = bk[c];  // bk carries bp for MODE 1
#pragma unroll
        for (int reg = 0; reg < 4; ++reg) {
          const int r = am0 + wr * 128 + m * 16 + lg * 4 + reg;
          if (r < M) fout[(size_t)r * 512 + c] = acc[m][n][reg] + bvv;
        }
      }
    }
  } else if (cls == 2) {  // V^T: m-axis = channels, n-axis = tokens
#pragma unroll
    for (int m = 0; m < 8; ++m) {
#pragma unroll
      for (int n = 0; n < 4; ++n) {
        const int tok = am0 + wc * 64 + n * 16 + l15;
        if (tok < M) {
          const int w = tok / 49, nt = tok - w * 49;
#pragma unroll
          for (int reg = 0; reg < 4; ++reg) {
            const int ch = bn0 + wr * 128 + m * 16 + lg * 4 + reg;
            const float v = acc[m][n][reg] + bv[ch];
            const int hh = ch >> 5, dd = ch & 31;
            vT_ws[(((size_t)w * 16 + hh) * 32 + dd) * 64 + nt] =
                __float2bfloat16(v);
          }
        }
      }
    }
  } else {
    const float* bb = (cls == 0) ? bk : bq;
    bf16* dp = (cls == 0) ? k_ws : q_ws;
    const float sc = (cls == 0) ? 1.0f : qscale;
#pragma unroll
    for (int m = 0; m < 8; ++m) {
#pragma unroll
      for (int n = 0; n < 4; ++n) {
        const int c = bn0 + wc * 64 + n * 16 + l15;
        const float bvv = bb[c];
        const int hh = c >> 5, dd = c & 31;
#pragma unroll
        for (int reg = 0; reg < 4; ++reg) {
          const int r = am0 + wr * 128 + m * 16 + lg * 4 + reg;
          if (r < M) {
            const int w = r / 49, nt = r - w * 49;
            dp[(((size_t)w * 16 + hh) * 49 + nt) * 32 + dd] =
                __float2bfloat16((acc[m][n][reg] + bvv) * sc);
          }
        }
      }
    }
  }
}

// ---------------- windowed attention: 1 head per wave, no barriers ---------
__global__ __launch_bounds__(256) void attn_win2(
    const bf16* __restrict__ q_ws, const bf16* __restrict__ k_ws,
    const bf16* __restrict__ vT_ws, const float* __restrict__ rpbL,
    const float* __restrict__ maskL, bf16* __restrict__ x_ws, int wstart) {
  __shared__ short sP[4][4096];
  const int tid = threadIdx.x, lane = tid & 63, wid = tid >> 6;
  const int l15 = lane & 15, lg = lane >> 4;
  const int wl = blockIdx.x;
  const int h = blockIdx.y * 4 + wid;
  const int wg = wstart + wl;
  char* Pl = (char*)sP[wid];
  const size_t base = ((size_t)wl * 16 + h) * 1568;
  const short8 z8 = (short8){0, 0, 0, 0, 0, 0, 0, 0};

  short8 qf[4], kf[4];
#pragma unroll
  for (int m = 0; m < 4; ++m) {
    const int r = m * 16 + l15;
    qf[m] = (r < 49) ? *(const short8*)(q_ws + base + r * 32 + lg * 8) : z8;
    kf[m] = (r < 49) ? *(const short8*)(k_ws + base + r * 32 + lg * 8) : z8;
  }
  f32x4 lc[4][4];
#pragma unroll
  for (int m = 0; m < 4; ++m)
#pragma unroll
    for (int n = 0; n < 4; ++n)
      lc[m][n] = __builtin_amdgcn_mfma_f32_16x16x32_bf16(
          qf[m], kf[n], (f32x4){0.f, 0.f, 0.f, 0.f}, 0, 0, 0);

  const f32x4* rbp = (const f32x4*)rpbL + (size_t)h * 1024 + lane;
  const f32x4* mkp = (const f32x4*)maskL + (size_t)(wg & 1023) * 1024 + lane;
#pragma unroll
  for (int m = 0; m < 4; ++m)
#pragma unroll
    for (int n = 0; n < 4; ++n) {
      const int mn = m * 4 + n;
      lc[m][n] += rbp[mn * 64] + mkp[mn * 64];
    }

#pragma unroll
  for (int m = 0; m < 4; ++m) {
#pragma unroll
    for (int reg = 0; reg < 4; ++reg) {
      float vmax = fmaxf(fmaxf(lc[m][0][reg], lc[m][1][reg]),
                         fmaxf(lc[m][2][reg], lc[m][3][reg]));
#pragma unroll
      for (int off = 1; off < 16; off <<= 1)
        vmax = fmaxf(vmax, __shfl_xor(vmax, off, 64));
      float e[4], ssum = 0.f;
#pragma unroll
      for (int n = 0; n < 4; ++n) {
        e[n] = __expf(lc[m][n][reg] - vmax);
        ssum += e[n];
      }
#pragma unroll
      for (int off = 1; off < 16; off <<= 1) ssum += __shfl_xor(ssum, off, 64);
      const float inv = __builtin_amdgcn_rcpf(ssum);
      const int i = m * 16 + lg * 4 + reg;
#pragma unroll
      for (int n = 0; n < 4; ++n) {
        const int cc = n * 16 + l15;
        *(unsigned short*)(Pl + i * 128 + ((2 * cc) ^ ((i & 7) << 4))) =
            f2b(e[n] * inv);
      }
    }
  }

  f32x4 xacc[4][2];
#pragma unroll
  for (int m = 0; m < 4; ++m)
#pragma unroll
    for (int n = 0; n < 2; ++n) xacc[m][n] = (f32x4){0.f, 0.f, 0.f, 0.f};
  const size_t vbase = ((size_t)wl * 16 + h) * 2048;
#pragma unroll
  for (int s = 0; s < 2; ++s) {
    short8 pf[4], vf[2];
#pragma unroll
    for (int m = 0; m < 4; ++m) {
      const int i = m * 16 + l15;
      pf[m] = *(const short8*)(Pl + i * 128 +
                               ((s * 64 + lg * 16) ^ ((i & 7) << 4)));
    }
#pragma unroll
    for (int n = 0; n < 2; ++n) {
      const int dd = n * 16 + l15;
      short8 vv = *(const short8*)(vT_ws + vbase + dd * 64 + s * 32 + lg * 8);
      if (s == 1) {
        if (lg == 3) vv = z8;
        else if (lg == 2) {
          vv[1] = 0; vv[2] = 0; vv[3] = 0; vv[4] = 0;
          vv[5] = 0; vv[6] = 0; vv[7] = 0;
        }
      }
      vf[n] = vv;
    }
#pragma unroll
    for (int m = 0; m < 4; ++m)
#pragma unroll
      for (int n = 0; n < 2; ++n)
        xacc[m][n] = __builtin_amdgcn_mfma_f32_16x16x32_bf16(
            pf[m], vf[n], xacc[m][n], 0, 0, 0);
  }

#pragma unroll
  for (int m = 0; m < 4; ++m)
#pragma unroll
    for (int n = 0; n < 2; ++n)
#pragma unroll
      for (int reg = 0; reg < 4; ++reg) {
        const int i = m * 16 + lg * 4 + reg;
        const int dd = n * 16 + l15;
        *(unsigned short*)(Pl + i * 80 + ((2 * dd) ^ ((i & 3) << 4))) =
            f2b(xacc[m][n][reg]);
      }
#pragma unroll
  for (int g = 0; g < 4; ++g) {
    const int row = g * 16 + (lane >> 2);
    if (row < 49) {
      const short8 xv = *(const short8*)(
          Pl + row * 80 + (((lane & 3) * 16) ^ ((row & 3) << 4)));
      *(short8*)(x_ws + ((size_t)wl * 49 + row) * 512 + h * 32 +
                 (lane & 3) * 8) = xv;
    }
  }
}

extern "C" void kernel_launch(void* const* d_in, const int* in_sizes, int n_in,
                              void* d_out, int out_size, void* d_ws,
                              size_t ws_size, hipStream_t stream) {
  const float* lf   = (const float*)d_in[0];
  const float* gfx  = (const float*)d_in[1];
  const float* mask = (const float*)d_in[2];
  const float* btab = (const float*)d_in[3];
  const float* Wk = (const float*)d_in[4];  const float* bk = (const float*)d_in[5];
  const float* Wq = (const float*)d_in[6];  const float* bq = (const float*)d_in[7];
  const float* Wv = (const float*)d_in[8];  const float* bv = (const float*)d_in[9];
  const float* Wp = (const float*)d_in[10]; const float* bp = (const float*)d_in[11];
  float* out = (float*)d_out;

  char* ws = (char*)d_ws;
  short* wbf = (short*)ws;  // 4 x 512x512 bf16 = 2 MB
  size_t off = (size_t)4 * 262144 * 2;
  float* rpbL = (float*)(ws + off); off += (size_t)16 * 4096 * 4;     // 256 KB
  float* maskL = (float*)(ws + off); off += (size_t)1024 * 4096 * 4;  // 16 MB

  const size_t perw = 2 * 49 * 1024 + 2 * 50176 + 65536;  // 266240 B/window
  size_t avail = (ws_size > off + 65536) ? ws_size - off - 65536 : 0;
  int CH = (int)((avail > 300000) ? (avail - 262144) / perw : 1);
  if (CH > 4096) CH = 4096;
  if (CH < 1) CH = 1;
  const int RWS = ((CH * 49 + 127) / 128) * 128;

  short* Al = (short*)(ws + off); off += (size_t)RWS * 1024;
  short* Ag = (short*)(ws + off); off += (size_t)RWS * 1024;
  bf16* q_ws = (bf16*)(ws + off); off += (size_t)CH * 50176;
  bf16* k_ws = (bf16*)(ws + off); off += (size_t)CH * 50176;
  bf16* vT_ws = (bf16*)(ws + off); off += (size_t)CH * 65536;
  bf16* x_ws = (bf16*)Al;  // alias: Al dead after gemm256<0>

  cvt_w_kernel<<<256, 256, 0, stream>>>(Wk, Wq, Wv, Wp, (bf16*)wbf);
  prep_rpbL<<<64, 256, 0, stream>>>(btab, rpbL);
  prep_maskL<<<4096, 256, 0, stream>>>(mask, maskL);

  const float qscale = 0.17677669529663687f;  // 1/sqrt(32)
  for (int wstart = 0; wstart < 4096; wstart += CH) {
    const int nwin = (4096 - wstart < CH) ? (4096 - wstart) : CH;
    const int M = nwin * 49;
    const int gy = (M + 255) / 256;
    const int cg = (M * 64 + 255) / 256;
    cvt_a<<<cg, 256, 0, stream>>>(lf + (size_t)wstart * 25088, Al, M);
    cvt_a<<<cg, 256, 0, stream>>>(gfx + (size_t)wstart * 25088, Ag, M);
    gemm256<0><<<6 * gy, 512, 0, stream>>>(Al, Ag, wbf, bk, bq, bv, qscale,
                                           k_ws, q_ws, vT_ws, nullptr, M);
    attn_win2<<<dim3(nwin, 4), 256, 0, stream>>>(q_ws, k_ws, vT_ws, rpbL,
                                                 maskL, x_ws, wstart);
    gemm256<1><<<2 * gy, 512, 0, stream>>>((const short*)x_ws, nullptr, wbf,
                                           bp, nullptr, nullptr, 1.0f, nullptr,
                                           nullptr, nullptr,
                                           out + (size_t)wstart * 25088, M);
  }
}